// Round 1
// baseline (645.740 us; speedup 1.0000x reference)
//
#include <hip/hip_runtime.h>

#define B_ 2
#define S_ 2048
#define D_ 2048
#define H_ 16
#define HD_ 128

typedef _Float16 fp16x2 __attribute__((ext_vector_type(2)));
typedef _Float16 fp16x4 __attribute__((ext_vector_type(4)));
typedef _Float16 fp16x8 __attribute__((ext_vector_type(8)));
typedef float f32x4 __attribute__((ext_vector_type(4)));

// ---------------- cast x fp32 -> fp16 ----------------
__global__ __launch_bounds__(256) void k_cast(const float* __restrict__ in,
                                              _Float16* __restrict__ out, int n4) {
  int i = blockIdx.x * 256 + threadIdx.x;
  if (i >= n4) return;
  f32x4 v = ((const f32x4*)in)[i];
  fp16x4 h = {(_Float16)v[0], (_Float16)v[1], (_Float16)v[2], (_Float16)v[3]};
  ((fp16x4*)out)[i] = h;
}

// ---------------- transpose+cast W[2048][2048] fp32 -> WT[n][k] fp16 ----------------
__global__ __launch_bounds__(256) void k_trw(const float* __restrict__ w,
                                             _Float16* __restrict__ wt) {
  __shared__ float tile[64][65];
  int k0 = blockIdx.y * 64, n0 = blockIdx.x * 64;
  int t = threadIdx.x;
  int r = t >> 2, c0 = (t & 3) * 16;
  const float* ip = w + (size_t)(k0 + r) * D_ + n0 + c0;
#pragma unroll
  for (int j = 0; j < 16; j += 4) {
    f32x4 v = *(const f32x4*)(ip + j);
    tile[r][c0 + j] = v[0]; tile[r][c0 + j + 1] = v[1];
    tile[r][c0 + j + 2] = v[2]; tile[r][c0 + j + 3] = v[3];
  }
  __syncthreads();
  _Float16* op = wt + (size_t)(n0 + r) * D_ + k0 + c0;
#pragma unroll
  for (int j = 0; j < 16; j += 8) {
    fp16x8 v;
#pragma unroll
    for (int q = 0; q < 8; ++q) v[q] = (_Float16)tile[c0 + j + q][r];
    *(fp16x8*)(op + j) = v;
  }
}

// ---------------- GEMM: C[M][N] = A16[M][K] * (BT16[N][K])^T, K=N=2048 ----------------
template <typename OUT>
__global__ __launch_bounds__(256) void k_gemm_bt(const _Float16* __restrict__ A,
                                                 const _Float16* __restrict__ BT,
                                                 OUT* __restrict__ C, int N) {
  __shared__ __align__(16) _Float16 lA[64][72];
  __shared__ __align__(16) _Float16 lB[64][72];
  const int t = threadIdx.x;
  const int m0 = blockIdx.y * 64, n0 = blockIdx.x * 64;
  const int lane = t & 63, w = t >> 6;
  const int wm = (w >> 1) * 32, wn = (w & 1) * 32;
  const int r = t >> 2, cb = (t & 3) * 16;
  const int l15 = lane & 15, g4 = (lane >> 4) * 4;
  f32x4 acc[2][2] = {};
  const _Float16* Ap = A + (size_t)(m0 + r) * D_ + cb;
  const _Float16* Bp = BT + (size_t)(n0 + r) * D_ + cb;
  for (int k0 = 0; k0 < D_; k0 += 64) {
    fp16x8 a0 = *(const fp16x8*)(Ap + k0);
    fp16x8 a1 = *(const fp16x8*)(Ap + k0 + 8);
    fp16x8 b0 = *(const fp16x8*)(Bp + k0);
    fp16x8 b1 = *(const fp16x8*)(Bp + k0 + 8);
    __syncthreads();
    *(fp16x8*)&lA[r][cb] = a0; *(fp16x8*)&lA[r][cb + 8] = a1;
    *(fp16x8*)&lB[r][cb] = b0; *(fp16x8*)&lB[r][cb + 8] = b1;
    __syncthreads();
#pragma unroll
    for (int ks = 0; ks < 4; ++ks) {
      const int kk = ks * 16 + g4;
      fp16x4 af0 = *(const fp16x4*)&lA[wm + l15][kk];
      fp16x4 af1 = *(const fp16x4*)&lA[wm + 16 + l15][kk];
      fp16x4 bf0 = *(const fp16x4*)&lB[wn + l15][kk];
      fp16x4 bf1 = *(const fp16x4*)&lB[wn + 16 + l15][kk];
      acc[0][0] = __builtin_amdgcn_mfma_f32_16x16x16f16(af0, bf0, acc[0][0], 0, 0, 0);
      acc[0][1] = __builtin_amdgcn_mfma_f32_16x16x16f16(af0, bf1, acc[0][1], 0, 0, 0);
      acc[1][0] = __builtin_amdgcn_mfma_f32_16x16x16f16(af1, bf0, acc[1][0], 0, 0, 0);
      acc[1][1] = __builtin_amdgcn_mfma_f32_16x16x16f16(af1, bf1, acc[1][1], 0, 0, 0);
    }
  }
#pragma unroll
  for (int mi = 0; mi < 2; ++mi)
#pragma unroll
    for (int ni = 0; ni < 2; ++ni) {
      size_t row = m0 + wm + 16 * mi + g4;
      size_t col = n0 + wn + 16 * ni + l15;
#pragma unroll
      for (int i = 0; i < 4; ++i)
        C[(row + i) * (size_t)N + col] = (OUT)acc[mi][ni][i];
    }
}

// ---------------- RoPE: in fp16 (B,S,H,HD) -> out fp16 (B,H,S,HD) ----------------
__global__ __launch_bounds__(256) void k_rope(const _Float16* __restrict__ in,
                                              const float* __restrict__ cosT,
                                              const float* __restrict__ sinT,
                                              _Float16* __restrict__ out) {
  int idx = blockIdx.x * 256 + threadIdx.x;  // B*S*H*64 = 4194304
  if (idx >= B_ * S_ * H_ * 64) return;
  int dp = idx & 63;
  int hh = (idx >> 6) & (H_ - 1);
  int s = (idx >> 10) & (S_ - 1);
  int b = idx >> 21;
  const _Float16* ip = in + (((size_t)b * S_ + s) * H_ + hh) * HD_ + 2 * dp;
  fp16x2 ab = *(const fp16x2*)ip;
  float a = (float)ab[0], bb = (float)ab[1];
  float c = cosT[s * 64 + dp], sn = sinT[s * 64 + dp];
  fp16x2 o = {(_Float16)(a * c - bb * sn), (_Float16)(a * sn + bb * c)};
  *(fp16x2*)(out + (((size_t)b * H_ + hh) * S_ + s) * HD_ + 2 * dp) = o;
}

// ---------------- V transpose: in fp16 (B,S,H,HD) -> Vt fp16 (B,H,HD,S) ----------------
__global__ __launch_bounds__(256) void k_trv(const _Float16* __restrict__ in,
                                             _Float16* __restrict__ out) {
  __shared__ __align__(16) _Float16 tile[64][72];
  int s0 = blockIdx.x * 64, d0 = blockIdx.y * 64;
  int bh = blockIdx.z;
  int b = bh >> 4, hh = bh & 15;
  int t = threadIdx.x;
  int r = t >> 2, c0 = (t & 3) * 16;
  const _Float16* ip = in + (((size_t)b * S_ + s0 + r) * H_ + hh) * HD_ + d0 + c0;
  *(fp16x8*)&tile[r][c0] = *(const fp16x8*)ip;
  *(fp16x8*)&tile[r][c0 + 8] = *(const fp16x8*)(ip + 8);
  __syncthreads();
  _Float16* op = out + ((size_t)bh * HD_ + d0 + r) * S_ + s0 + c0;
#pragma unroll
  for (int j = 0; j < 16; j += 8) {
    fp16x8 v;
#pragma unroll
    for (int q = 0; q < 8; ++q) v[q] = tile[c0 + j + q][r];
    *(fp16x8*)(op + j) = v;
  }
}

// ---------------- block-sparse flash attention ----------------
// Q,K: (B,H,S,HD) fp16;  Vt: (B,H,HD,S) fp16;  Oa: (B,S,D) fp16
__global__ __launch_bounds__(64) void k_attn(const _Float16* __restrict__ Q,
                                             const _Float16* __restrict__ K,
                                             const _Float16* __restrict__ Vt,
                                             _Float16* __restrict__ Oa) {
  const int qb = blockIdx.x, hh = blockIdx.y, b = blockIdx.z;
  const int lane = threadIdx.x;
  const int l15 = lane & 15, g4 = (lane >> 4) * 4;
  const size_t bh = (size_t)b * H_ + hh;
  const float scale = 0.08838834764831845f;  // 1/sqrt(128)
  const _Float16* Qp = Q + (bh * S_ + (size_t)qb * 16 + l15) * HD_ + g4;
  fp16x4 qf[8];
#pragma unroll
  for (int d = 0; d < 8; ++d) qf[d] = *(const fp16x4*)(Qp + 16 * d);
  f32x4 o[8] = {};
  float mrun = -3.0e38f, lsum = 0.f;

  auto process = [&](int kb) {
    const _Float16* Kp = K + (bh * S_ + (size_t)kb * 16 + l15) * HD_ + g4;
    f32x4 st = {};
#pragma unroll
    for (int d = 0; d < 8; ++d) {
      fp16x4 kf = *(const fp16x4*)(Kp + 16 * d);
      st = __builtin_amdgcn_mfma_f32_16x16x16f16(kf, qf[d], st, 0, 0, 0);
    }
    float s0 = st[0] * scale, s1 = st[1] * scale, s2 = st[2] * scale, s3 = st[3] * scale;
    float bm = fmaxf(fmaxf(s0, s1), fmaxf(s2, s3));
    bm = fmaxf(bm, __shfl_xor(bm, 16));
    bm = fmaxf(bm, __shfl_xor(bm, 32));
    float mnew = fmaxf(mrun, bm);
    float corr = __expf(mrun - mnew);
    float p0 = __expf(s0 - mnew), p1 = __expf(s1 - mnew);
    float p2 = __expf(s2 - mnew), p3 = __expf(s3 - mnew);
    float ps = p0 + p1 + p2 + p3;
    ps += __shfl_xor(ps, 16);
    ps += __shfl_xor(ps, 32);
    lsum = lsum * corr + ps;
    mrun = mnew;
    f32x4 c4;
#pragma unroll
    for (int i = 0; i < 4; ++i) c4[i] = __shfl(corr, g4 + i);
#pragma unroll
    for (int ni = 0; ni < 8; ++ni) {
      o[ni][0] *= c4[0]; o[ni][1] *= c4[1]; o[ni][2] *= c4[2]; o[ni][3] *= c4[3];
    }
    fp16x4 ph = {(_Float16)p0, (_Float16)p1, (_Float16)p2, (_Float16)p3};
    const _Float16* Vp = Vt + (bh * HD_ + l15) * S_ + (size_t)kb * 16 + g4;
#pragma unroll
    for (int ni = 0; ni < 8; ++ni) {
      fp16x4 vf = *(const fp16x4*)(Vp + (size_t)16 * ni * S_);
      o[ni] = __builtin_amdgcn_mfma_f32_16x16x16f16(ph, vf, o[ni], 0, 0, 0);
    }
  };

  const int w0 = qb & ~3;
  for (int kb = 3; kb < w0; kb += 4) process(kb);  // global cols strictly below window
  for (int kb = w0; kb <= qb; ++kb) process(kb);   // local causal window (block granularity)

  float inv = 1.f / lsum;
  f32x4 li;
#pragma unroll
  for (int i = 0; i < 4; ++i) li[i] = __shfl(inv, g4 + i);
  _Float16* Op = Oa + ((size_t)b * S_ + (size_t)qb * 16 + g4) * D_ + (size_t)hh * HD_ + l15;
#pragma unroll
  for (int ni = 0; ni < 8; ++ni)
#pragma unroll
    for (int i = 0; i < 4; ++i)
      Op[(size_t)i * D_ + 16 * ni] = (_Float16)(o[ni][i] * li[i]);
}

extern "C" void kernel_launch(void* const* d_in, const int* in_sizes, int n_in,
                              void* d_out, int out_size, void* d_ws, size_t ws_size,
                              hipStream_t stream) {
  const float* x = (const float*)d_in[0];
  const float* cosT = (const float*)d_in[1];
  const float* sinT = (const float*)d_in[2];
  const float* wq = (const float*)d_in[3];
  const float* wk = (const float*)d_in[4];
  const float* wv = (const float*)d_in[5];
  const float* wo = (const float*)d_in[6];
  float* out = (float*)d_out;
  char* ws = (char*)d_ws;

  _Float16* x16 = (_Float16*)(ws);                    // 16MB, reused as attn out
  _Float16* wtq = (_Float16*)(ws + (16ull << 20));    // 8MB each
  _Float16* wtk = (_Float16*)(ws + (24ull << 20));
  _Float16* wtv = (_Float16*)(ws + (32ull << 20));
  _Float16* wto = (_Float16*)(ws + (40ull << 20));
  _Float16* Q16 = (_Float16*)(ws + (48ull << 20));    // 16MB
  _Float16* K16 = (_Float16*)(ws + (64ull << 20));    // 16MB
  _Float16* Vt16 = (_Float16*)(ws + (80ull << 20));   // 16MB
  _Float16* tmp16 = (_Float16*)(ws + (96ull << 20));  // 16MB -> 112MB total

  k_cast<<<8192, 256, 0, stream>>>(x, x16, (B_ * S_ * D_) / 4);
  dim3 gw(32, 32);
  k_trw<<<gw, 256, 0, stream>>>(wq, wtq);
  k_trw<<<gw, 256, 0, stream>>>(wk, wtk);
  k_trw<<<gw, 256, 0, stream>>>(wv, wtv);
  k_trw<<<gw, 256, 0, stream>>>(wo, wto);

  dim3 gg(D_ / 64, (B_ * S_) / 64);  // (32, 64)
  k_gemm_bt<_Float16><<<gg, 256, 0, stream>>>(x16, wtq, tmp16, D_);
  k_rope<<<16384, 256, 0, stream>>>(tmp16, cosT, sinT, Q16);
  k_gemm_bt<_Float16><<<gg, 256, 0, stream>>>(x16, wtk, tmp16, D_);
  k_rope<<<16384, 256, 0, stream>>>(tmp16, cosT, sinT, K16);
  k_gemm_bt<_Float16><<<gg, 256, 0, stream>>>(x16, wtv, tmp16, D_);
  dim3 gv(S_ / 64, HD_ / 64, B_ * H_);  // (32, 2, 32)
  k_trv<<<gv, 256, 0, stream>>>(tmp16, Vt16);

  _Float16* attn16 = x16;  // x16 no longer needed
  k_attn<<<dim3(S_ / 16, H_, B_), 64, 0, stream>>>(Q16, K16, Vt16, attn16);

  k_gemm_bt<float><<<gg, 256, 0, stream>>>(attn16, wto, out, D_);
}

// Round 2
// 440.626 us; speedup vs baseline: 1.4655x; 1.4655x over previous
//
#include <hip/hip_runtime.h>

#define B_ 2
#define S_ 2048
#define D_ 2048
#define H_ 16
#define HD_ 128

typedef _Float16 fp16x2 __attribute__((ext_vector_type(2)));
typedef _Float16 fp16x4 __attribute__((ext_vector_type(4)));
typedef _Float16 fp16x8 __attribute__((ext_vector_type(8)));
typedef float f32x4 __attribute__((ext_vector_type(4)));

__device__ __forceinline__ void gl_lds16(const _Float16* g, _Float16* l) {
  __builtin_amdgcn_global_load_lds((const __attribute__((address_space(1))) void*)g,
                                   (__attribute__((address_space(3))) void*)l, 16, 0, 0);
}

// ---------------- cast x fp32 -> fp16 ----------------
__global__ __launch_bounds__(256) void k_cast(const float* __restrict__ in,
                                              _Float16* __restrict__ out, int n4) {
  int i = blockIdx.x * 256 + threadIdx.x;
  if (i >= n4) return;
  f32x4 v = ((const f32x4*)in)[i];
  fp16x4 h = {(_Float16)v[0], (_Float16)v[1], (_Float16)v[2], (_Float16)v[3]};
  ((fp16x4*)out)[i] = h;
}

// ---------------- transpose+cast 4x W[2048][2048] fp32 -> WT[n][k] fp16 ----------------
__global__ __launch_bounds__(256) void k_trw4(const float* __restrict__ w0,
                                              const float* __restrict__ w1,
                                              const float* __restrict__ w2,
                                              const float* __restrict__ w3,
                                              _Float16* __restrict__ o0,
                                              _Float16* __restrict__ o1,
                                              _Float16* __restrict__ o2,
                                              _Float16* __restrict__ o3) {
  __shared__ float tile[64][65];
  const float* w = (blockIdx.z == 0) ? w0 : (blockIdx.z == 1) ? w1 : (blockIdx.z == 2) ? w2 : w3;
  _Float16* wt = (blockIdx.z == 0) ? o0 : (blockIdx.z == 1) ? o1 : (blockIdx.z == 2) ? o2 : o3;
  int k0 = blockIdx.y * 64, n0 = blockIdx.x * 64;
  int t = threadIdx.x;
  int r = t >> 2, c0 = (t & 3) * 16;
  const float* ip = w + (size_t)(k0 + r) * D_ + n0 + c0;
#pragma unroll
  for (int j = 0; j < 16; j += 4) {
    f32x4 v = *(const f32x4*)(ip + j);
    tile[r][c0 + j] = v[0]; tile[r][c0 + j + 1] = v[1];
    tile[r][c0 + j + 2] = v[2]; tile[r][c0 + j + 3] = v[3];
  }
  __syncthreads();
  _Float16* op = wt + (size_t)(n0 + r) * D_ + k0 + c0;
#pragma unroll
  for (int j = 0; j < 16; j += 8) {
    fp16x8 v;
#pragma unroll
    for (int q = 0; q < 8; ++q) v[q] = (_Float16)tile[c0 + j + q][r];
    *(fp16x8*)(op + j) = v;
  }
}

// ---------------- GEMM (m97 structure): C[M][N] = A16[M][2048] * (BT16[N][2048])^T ----------------
// 128x128 tile, BK=64, 4 waves (2x2), global_load_lds width-16, 16x16x32 f16 MFMA.
template <typename OUT>
__global__ __launch_bounds__(256) void k_gemm_bt(const _Float16* __restrict__ A,
                                                 const _Float16* __restrict__ BT,
                                                 OUT* __restrict__ C, int N) {
  __shared__ __align__(16) _Float16 lA[128 * 64];
  __shared__ __align__(16) _Float16 lB[128 * 64];
  const int t = threadIdx.x;
  const int m0 = blockIdx.y * 128, n0 = blockIdx.x * 128;
  const int lane = t & 63, w = t >> 6;
  const int l15 = lane & 15, lg = lane >> 4;
  const int wm = (w >> 1) * 64, wn = (w & 1) * 64;
  // staging coords: thread t covers row (i*32 + t/8), cols (t&7)*8 .. +7 of the 128x64 tile
  const int rs = t >> 3, cs = (t & 7) * 8;
  const _Float16* Ag = A + (size_t)(m0 + rs) * 2048 + cs;
  const _Float16* Bg = BT + (size_t)(n0 + rs) * 2048 + cs;
  _Float16* lAw = lA + w * 512;  // wave-uniform LDS base (HW adds lane*16B)
  _Float16* lBw = lB + w * 512;
  f32x4 acc[4][4] = {};
  for (int k0 = 0; k0 < 2048; k0 += 64) {
#pragma unroll
    for (int i = 0; i < 4; ++i) {
      gl_lds16(Ag + k0 + (size_t)i * 32 * 2048, lAw + i * 2048);
      gl_lds16(Bg + k0 + (size_t)i * 32 * 2048, lBw + i * 2048);
    }
    __syncthreads();  // drains vmcnt: LDS tile valid
#pragma unroll
    for (int ks = 0; ks < 2; ++ks) {
      const int ko = ks * 32 + 8 * lg;
      fp16x8 af[4], bf[4];
#pragma unroll
      for (int mi = 0; mi < 4; ++mi)
        af[mi] = *(const fp16x8*)&lA[(wm + mi * 16 + l15) * 64 + ko];
#pragma unroll
      for (int ni = 0; ni < 4; ++ni)
        bf[ni] = *(const fp16x8*)&lB[(wn + ni * 16 + l15) * 64 + ko];
#pragma unroll
      for (int mi = 0; mi < 4; ++mi)
#pragma unroll
        for (int ni = 0; ni < 4; ++ni)
          acc[mi][ni] = __builtin_amdgcn_mfma_f32_16x16x32_f16(af[mi], bf[ni], acc[mi][ni], 0, 0, 0);
    }
    __syncthreads();  // all waves done reading before next overwrite
  }
#pragma unroll
  for (int mi = 0; mi < 4; ++mi)
#pragma unroll
    for (int ni = 0; ni < 4; ++ni) {
      size_t row = m0 + wm + 16 * mi + 4 * lg;
      size_t col = n0 + wn + 16 * ni + l15;
#pragma unroll
      for (int i = 0; i < 4; ++i)
        C[(row + i) * (size_t)N + col] = (OUT)acc[mi][ni][i];
    }
}

// ---------------- RoPE: in fp16 (B,S,H,HD) -> out fp16 (B,H,S,HD) ----------------
__global__ __launch_bounds__(256) void k_rope(const _Float16* __restrict__ in,
                                              const float* __restrict__ cosT,
                                              const float* __restrict__ sinT,
                                              _Float16* __restrict__ out) {
  int idx = blockIdx.x * 256 + threadIdx.x;
  if (idx >= B_ * S_ * H_ * 64) return;
  int dp = idx & 63;
  int hh = (idx >> 6) & (H_ - 1);
  int s = (idx >> 10) & (S_ - 1);
  int b = idx >> 21;
  const _Float16* ip = in + (((size_t)b * S_ + s) * H_ + hh) * HD_ + 2 * dp;
  fp16x2 ab = *(const fp16x2*)ip;
  float a = (float)ab[0], bb = (float)ab[1];
  float c = cosT[s * 64 + dp], sn = sinT[s * 64 + dp];
  fp16x2 o = {(_Float16)(a * c - bb * sn), (_Float16)(a * sn + bb * c)};
  *(fp16x2*)(out + (((size_t)b * H_ + hh) * S_ + s) * HD_ + 2 * dp) = o;
}

// ---------------- V transpose: in fp16 (B,S,H,HD) -> Vt fp16 (B,H,HD,S) ----------------
__global__ __launch_bounds__(256) void k_trv(const _Float16* __restrict__ in,
                                             _Float16* __restrict__ out) {
  __shared__ __align__(16) _Float16 tile[64][72];
  int s0 = blockIdx.x * 64, d0 = blockIdx.y * 64;
  int bh = blockIdx.z;
  int b = bh >> 4, hh = bh & 15;
  int t = threadIdx.x;
  int r = t >> 2, c0 = (t & 3) * 16;
  const _Float16* ip = in + (((size_t)b * S_ + s0 + r) * H_ + hh) * HD_ + d0 + c0;
  *(fp16x8*)&tile[r][c0] = *(const fp16x8*)ip;
  *(fp16x8*)&tile[r][c0 + 8] = *(const fp16x8*)(ip + 8);
  __syncthreads();
  _Float16* op = out + ((size_t)bh * HD_ + d0 + r) * S_ + s0 + c0;
#pragma unroll
  for (int j = 0; j < 16; j += 8) {
    fp16x8 v;
#pragma unroll
    for (int q = 0; q < 8; ++q) v[q] = tile[c0 + j + q][r];
    *(fp16x8*)(op + j) = v;
  }
}

// ---------------- block-sparse flash attention, 4-way split-K per qb ----------------
// Q,K: (B,H,S,HD) fp16;  Vt: (B,H,HD,S) fp16;  Oa: (B,S,D) fp16
__global__ __launch_bounds__(256) void k_attn(const _Float16* __restrict__ Q,
                                              const _Float16* __restrict__ K,
                                              const _Float16* __restrict__ Vt,
                                              _Float16* __restrict__ Oa) {
  __shared__ float o_sh[4][16][132];
  __shared__ float ml_sh[4][2][16];
  const int qb = (S_ / 16 - 1) - blockIdx.x;  // reversed: long blocks first
  const int hh = blockIdx.y, b = blockIdx.z;
  const int t = threadIdx.x;
  const int w = t >> 6, lane = t & 63;
  const int l15 = lane & 15, g4 = (lane >> 4) * 4;
  const size_t bh = (size_t)b * H_ + hh;
  const float scale = 0.08838834764831845f;  // 1/sqrt(128)
  const _Float16* Qp = Q + (bh * S_ + (size_t)qb * 16 + l15) * HD_ + g4;
  fp16x4 qf[8];
#pragma unroll
  for (int d = 0; d < 8; ++d) qf[d] = *(const fp16x4*)(Qp + 16 * d);
  f32x4 o[8] = {};
  float mrun = -3.0e38f, lsum = 0.f;

  auto process = [&](int kb) {
    const _Float16* Kp = K + (bh * S_ + (size_t)kb * 16 + l15) * HD_ + g4;
    f32x4 st = {};
#pragma unroll
    for (int d = 0; d < 8; ++d) {
      fp16x4 kf = *(const fp16x4*)(Kp + 16 * d);
      st = __builtin_amdgcn_mfma_f32_16x16x16f16(kf, qf[d], st, 0, 0, 0);
    }
    float s0 = st[0] * scale, s1 = st[1] * scale, s2 = st[2] * scale, s3 = st[3] * scale;
    float bm = fmaxf(fmaxf(s0, s1), fmaxf(s2, s3));
    bm = fmaxf(bm, __shfl_xor(bm, 16));
    bm = fmaxf(bm, __shfl_xor(bm, 32));
    float mnew = fmaxf(mrun, bm);
    float corr = __expf(mrun - mnew);
    float p0 = __expf(s0 - mnew), p1 = __expf(s1 - mnew);
    float p2 = __expf(s2 - mnew), p3 = __expf(s3 - mnew);
    float ps = p0 + p1 + p2 + p3;
    ps += __shfl_xor(ps, 16);
    ps += __shfl_xor(ps, 32);
    lsum = lsum * corr + ps;
    mrun = mnew;
    f32x4 c4;
#pragma unroll
    for (int i = 0; i < 4; ++i) c4[i] = __shfl(corr, g4 + i);
#pragma unroll
    for (int ni = 0; ni < 8; ++ni) {
      o[ni][0] *= c4[0]; o[ni][1] *= c4[1]; o[ni][2] *= c4[2]; o[ni][3] *= c4[3];
    }
    fp16x4 ph = {(_Float16)p0, (_Float16)p1, (_Float16)p2, (_Float16)p3};
    const _Float16* Vp = Vt + (bh * HD_ + l15) * S_ + (size_t)kb * 16 + g4;
#pragma unroll
    for (int ni = 0; ni < 8; ++ni) {
      fp16x4 vf = *(const fp16x4*)(Vp + (size_t)16 * ni * S_);
      o[ni] = __builtin_amdgcn_mfma_f32_16x16x16f16(ph, vf, o[ni], 0, 0, 0);
    }
  };

  // block list for qb: globals {3,7,...,w0-1} (g of them) ++ locals {w0..qb}
  const int w0 = qb & ~3;
  const int g = qb >> 2;
  const int nb = g + (qb - w0) + 1;
  for (int idx = w; idx < nb; idx += 4) {
    int kb = (idx < g) ? (4 * idx + 3) : (w0 + idx - g);
    process(kb);
  }

  // stash partials
  if (lane < 16) { ml_sh[w][0][lane] = mrun; ml_sh[w][1][lane] = lsum; }
#pragma unroll
  for (int ni = 0; ni < 8; ++ni)
#pragma unroll
    for (int i = 0; i < 4; ++i)
      o_sh[w][g4 + i][16 * ni + l15] = o[ni][i];
  __syncthreads();

  // merge 4 partials: thread t -> row r = t>>4, cols cb..cb+7
  const int r = t >> 4, cb = (t & 15) * 8;
  float m0 = ml_sh[0][0][r], m1 = ml_sh[1][0][r], m2 = ml_sh[2][0][r], m3 = ml_sh[3][0][r];
  float M = fmaxf(fmaxf(m0, m1), fmaxf(m2, m3));
  float e0 = __expf(m0 - M), e1 = __expf(m1 - M), e2 = __expf(m2 - M), e3 = __expf(m3 - M);
  float ltot = ml_sh[0][1][r] * e0 + ml_sh[1][1][r] * e1 + ml_sh[2][1][r] * e2 + ml_sh[3][1][r] * e3;
  float inv = 1.f / ltot;
  fp16x8 ov;
#pragma unroll
  for (int j = 0; j < 8; ++j) {
    float v = e0 * o_sh[0][r][cb + j] + e1 * o_sh[1][r][cb + j] +
              e2 * o_sh[2][r][cb + j] + e3 * o_sh[3][r][cb + j];
    ov[j] = (_Float16)(v * inv);
  }
  *(fp16x8*)(Oa + ((size_t)b * S_ + (size_t)qb * 16 + r) * D_ + (size_t)hh * HD_ + cb) = ov;
}

extern "C" void kernel_launch(void* const* d_in, const int* in_sizes, int n_in,
                              void* d_out, int out_size, void* d_ws, size_t ws_size,
                              hipStream_t stream) {
  const float* x = (const float*)d_in[0];
  const float* cosT = (const float*)d_in[1];
  const float* sinT = (const float*)d_in[2];
  const float* wq = (const float*)d_in[3];
  const float* wk = (const float*)d_in[4];
  const float* wv = (const float*)d_in[5];
  const float* wo = (const float*)d_in[6];
  float* out = (float*)d_out;
  char* ws = (char*)d_ws;

  _Float16* x16 = (_Float16*)(ws);                    // 16MB, reused as attn out
  _Float16* wtq = (_Float16*)(ws + (16ull << 20));    // 8MB each
  _Float16* wtk = (_Float16*)(ws + (24ull << 20));
  _Float16* wtv = (_Float16*)(ws + (32ull << 20));
  _Float16* wto = (_Float16*)(ws + (40ull << 20));
  _Float16* Q16 = (_Float16*)(ws + (48ull << 20));    // 16MB
  _Float16* K16 = (_Float16*)(ws + (64ull << 20));    // 16MB
  _Float16* Vt16 = (_Float16*)(ws + (80ull << 20));   // 16MB
  _Float16* tmp16 = (_Float16*)(ws + (96ull << 20));  // 16MB -> 112MB total

  k_cast<<<8192, 256, 0, stream>>>(x, x16, (B_ * S_ * D_) / 4);
  k_trw4<<<dim3(32, 32, 4), 256, 0, stream>>>(wq, wk, wv, wo, wtq, wtk, wtv, wto);

  dim3 gg(D_ / 128, (B_ * S_) / 128);  // (16, 32)
  k_gemm_bt<_Float16><<<gg, 256, 0, stream>>>(x16, wtq, tmp16, D_);
  k_rope<<<16384, 256, 0, stream>>>(tmp16, cosT, sinT, Q16);
  k_gemm_bt<_Float16><<<gg, 256, 0, stream>>>(x16, wtk, tmp16, D_);
  k_rope<<<16384, 256, 0, stream>>>(tmp16, cosT, sinT, K16);
  k_gemm_bt<_Float16><<<gg, 256, 0, stream>>>(x16, wtv, tmp16, D_);
  dim3 gv(S_ / 64, HD_ / 64, B_ * H_);  // (32, 2, 32)
  k_trv<<<gv, 256, 0, stream>>>(tmp16, Vt16);

  _Float16* attn16 = x16;  // x16 no longer needed
  k_attn<<<dim3(S_ / 16, H_, B_), 256, 0, stream>>>(Q16, K16, Vt16, attn16);

  k_gemm_bt<float><<<gg, 256, 0, stream>>>(attn16, wto, out, D_);
}